// Round 9
// baseline (159.574 us; speedup 1.0000x reference)
//
#include <hip/hip_runtime.h>
#include <hip/hip_bf16.h>

typedef __attribute__((ext_vector_type(8))) short short8;
typedef __attribute__((ext_vector_type(4))) float f32x4;
typedef __attribute__((ext_vector_type(4))) unsigned int u32x4;

#define B_DIM   8192
#define IN_DIM  2048
#define OUT_DIM 1024

#define BM 256
#define BN 128
#define KS 32                      // K-step per iteration
#define NT (IN_DIM / KS)           // 64 iterations
#define B_VAR_E (BN * KS)          // 4096 elems = 8 KB per variant
#define B_BUF_E (2 * B_VAR_E)      // Bw + Ba = 16 KB per buffer
#define LDS_BYTES (2 * B_BUF_E * 2)   // 32768 = 32 KiB (B only; A lives in regs)

__device__ __forceinline__ unsigned short f2bf(float f) {
    union { float f; unsigned u; } v; v.f = f;
    unsigned u = v.u;
    unsigned r = (u + 0x7FFFu + ((u >> 16) & 1u)) >> 16;   // RNE
    return (unsigned short)r;
}

// Bw[o][i] = W[i][o] ; Ba[o][i] = 0.1*|W[i][o]|   (DELTA folded)
__global__ void prep_w(const float* __restrict__ W, unsigned short* __restrict__ Bw,
                       unsigned short* __restrict__ Ba) {
    __shared__ float tile[32][33];
    int o0 = blockIdx.x * 32;
    int i0 = blockIdx.y * 32;
    int tx = threadIdx.x, ty = threadIdx.y;   // 32 x 8
    #pragma unroll
    for (int r = 0; r < 4; ++r) {
        int ii = ty + r * 8;
        tile[ii][tx] = W[(size_t)(i0 + ii) * OUT_DIM + o0 + tx];
    }
    __syncthreads();
    #pragma unroll
    for (int r = 0; r < 4; ++r) {
        int oo = ty + r * 8;
        float wv = tile[tx][oo];
        Bw[(size_t)(o0 + oo) * IN_DIM + i0 + tx] = f2bf(wv);
        Ba[(size_t)(o0 + oo) * IN_DIM + i0 + tx] = f2bf(0.1f * fabsf(wv));
    }
}

// B staging (R8-proven, 0 conflicts): one variant tile 128x32 = 8 KB =
// 512 threads x 16 B. Linear LDS dest; XOR-swizzled global SOURCE slot.
__device__ __forceinline__ void stageB1(const unsigned short* __restrict__ g,
                                        unsigned short* lds_dst,
                                        int col0, int k0, int tid) {
    int row  = tid >> 2;                     // 0..127
    int slot = (tid & 3) ^ ((row >> 1) & 3);
    __builtin_amdgcn_global_load_lds(
        (const __attribute__((address_space(1))) void*)(g + (size_t)(col0 + row) * IN_DIM + k0 + slot * 8),
        (__attribute__((address_space(3))) void*)(lds_dst + (size_t)tid * 8),
        16, 0, 0);
}

// B fragment read, inverse swizzle (R8-proven)
__device__ __forceinline__ short8 read_frag(const unsigned short* buf, int row,
                                            int lq) {
    int sl = lq ^ ((row >> 1) & 3);
    return *reinterpret_cast<const short8*>(buf + row * KS + sl * 8);
}

// one K=32 iteration: B via LDS double-buffer, A direct global->reg->cvt.
// Queue discipline: [x(t):8] outstanding on entry; issue [B(t+1):2, x(t+1):8];
// compiler auto-waits vmcnt(10) before using x(t); manual vmcnt(8) retires
// B(t+1) before the barrier while x(t+1) stays in flight.
#define ITER(T_, BCUR, BNXT, XCUR, XNXT) do {                                  \
    int t_ = (T_);                                                             \
    bool more_ = (t_ + 1 < NT);                                                \
    if (more_) {                                                               \
        stageB1(Bw, (BNXT),           col0, (t_ + 1) * KS, tid);               \
        stageB1(Ba, (BNXT) + B_VAR_E, col0, (t_ + 1) * KS, tid);               \
        _Pragma("unroll") for (int m_ = 0; m_ < 4; ++m_) {                     \
            (XNXT)[2*m_]   = *reinterpret_cast<const float4*>(px[m_] + (t_+1)*KS);     \
            (XNXT)[2*m_+1] = *reinterpret_cast<const float4*>(px[m_] + (t_+1)*KS + 4); \
        }                                                                      \
    }                                                                          \
    short8 fb0[4], fb1[4];                                                     \
    _Pragma("unroll") for (int n_ = 0; n_ < 4; ++n_) {                         \
        fb0[n_] = read_frag((BCUR),           rowB + n_ * 16, lq);             \
        fb1[n_] = read_frag((BCUR) + B_VAR_E, rowB + n_ * 16, lq);             \
    }                                                                          \
    __builtin_amdgcn_s_setprio(1);                                             \
    _Pragma("unroll") for (int m_ = 0; m_ < 4; ++m_) {                         \
        unsigned dm_[4], da_[4];                                               \
        _Pragma("unroll") for (int q_ = 0; q_ < 2; ++q_) {                     \
            float4 v_ = (XCUR)[2*m_ + q_];                                     \
            float w0_ = v_.x >= -1.0f ? v_.x : 0.0f;                           \
            float w1_ = v_.y >= -1.0f ? v_.y : 0.0f;                           \
            float w2_ = v_.z >= -1.0f ? v_.z : 0.0f;                           \
            float w3_ = v_.w >= -1.0f ? v_.w : 0.0f;                           \
            float a0_ = -fabsf(v_.x), a1_ = -fabsf(v_.y);                      \
            float a2_ = -fabsf(v_.z), a3_ = -fabsf(v_.w);                      \
            asm("v_cvt_pk_bf16_f32 %0,%1,%2" : "=v"(dm_[2*q_  ]) : "v"(w0_), "v"(w1_)); \
            asm("v_cvt_pk_bf16_f32 %0,%1,%2" : "=v"(dm_[2*q_+1]) : "v"(w2_), "v"(w3_)); \
            asm("v_cvt_pk_bf16_f32 %0,%1,%2" : "=v"(da_[2*q_  ]) : "v"(a0_), "v"(a1_)); \
            asm("v_cvt_pk_bf16_f32 %0,%1,%2" : "=v"(da_[2*q_+1]) : "v"(a2_), "v"(a3_)); \
        }                                                                      \
        u32x4 um_ = {dm_[0], dm_[1], dm_[2], dm_[3]};                          \
        u32x4 ua_ = {da_[0], da_[1], da_[2], da_[3]};                          \
        short8 fm_ = *reinterpret_cast<short8*>(&um_);                         \
        short8 fa_ = *reinterpret_cast<short8*>(&ua_);                         \
        _Pragma("unroll") for (int n_ = 0; n_ < 4; ++n_) {                     \
            acc[m_][n_] = __builtin_amdgcn_mfma_f32_16x16x32_bf16(             \
                fm_, fb0[n_], acc[m_][n_], 0, 0, 0);                           \
            acc[m_][n_] = __builtin_amdgcn_mfma_f32_16x16x32_bf16(             \
                fa_, fb1[n_], acc[m_][n_], 0, 0, 0);                           \
        }                                                                      \
    }                                                                          \
    __builtin_amdgcn_s_setprio(0);                                             \
    if (more_) {                                                               \
        asm volatile("s_waitcnt vmcnt(8)" ::: "memory");                       \
        __builtin_amdgcn_s_barrier();                                          \
    }                                                                          \
} while (0)

// out[b][o] = sum_i [ mask(x)*x*W + (-|x|)*(0.1|W|) ] + 1e-5
__global__ __launch_bounds__(512) void gemm_fused(const float* __restrict__ x,
                                                  const unsigned short* __restrict__ Bw,
                                                  const unsigned short* __restrict__ Ba,
                                                  float* __restrict__ C) {
    extern __shared__ __align__(16) unsigned short smem[];
    unsigned short* sB = smem;                    // [2][B_BUF_E]

    // XCD colocation (R3-verified): each XCD owns 4 contiguous by-panels
    int bid = blockIdx.x;
    int xcd = bid & 7;
    int idx = bid >> 3;            // 0..31
    int by  = xcd * 4 + (idx >> 3);
    int bx  = idx & 7;
    int row0 = by * BM;
    int col0 = bx * BN;

    int tid  = threadIdx.x;
    int lane = tid & 63;
    int w    = tid >> 6;           // 0..7
    int wr   = w >> 1;             // 0..3
    int wc   = w & 1;              // 0..1
    int lr   = lane & 15;
    int lq   = lane >> 4;          // 0..3
    int rowB = wc * 64 + lr;

    // per-m x row pointers in A-fragment layout: row=lane&15, k=lq*8+j
    const float* px[4];
    #pragma unroll
    for (int m = 0; m < 4; ++m)
        px[m] = x + (size_t)(row0 + wr * 64 + m * 16 + lr) * IN_DIM + lq * 8;

    f32x4 acc[4][4];
    #pragma unroll
    for (int m = 0; m < 4; ++m)
        #pragma unroll
        for (int n = 0; n < 4; ++n)
            acc[m][n] = (f32x4){0.f, 0.f, 0.f, 0.f};

    float4 xv0[8], xv1[8];

    // prologue: B(0) staged, x(0) issued; vmcnt(8) retires B(0), x(0) in flight
    stageB1(Bw, sB,           col0, 0, tid);
    stageB1(Ba, sB + B_VAR_E, col0, 0, tid);
    #pragma unroll
    for (int m = 0; m < 4; ++m) {
        xv0[2*m]   = *reinterpret_cast<const float4*>(px[m]);
        xv0[2*m+1] = *reinterpret_cast<const float4*>(px[m] + 4);
    }
    asm volatile("s_waitcnt vmcnt(8)" ::: "memory");
    __builtin_amdgcn_s_barrier();

    #pragma unroll 1
    for (int T = 0; T < NT; T += 2) {
        ITER(T,     sB,           sB + B_BUF_E, xv0, xv1);
        ITER(T + 1, sB + B_BUF_E, sB,           xv1, xv0);
    }

    // epilogue: C/D layout col = lane&15, row = (lane>>4)*4 + reg
    #pragma unroll
    for (int m = 0; m < 4; ++m) {
        #pragma unroll
        for (int n = 0; n < 4; ++n) {
            int col  = col0 + wc * 64 + n * 16 + lr;
            int rowb = row0 + wr * 64 + m * 16 + lq * 4;
            #pragma unroll
            for (int j = 0; j < 4; ++j)
                C[(size_t)(rowb + j) * OUT_DIM + col] = acc[m][n][j] + 1e-5f;
        }
    }
}

extern "C" void kernel_launch(void* const* d_in, const int* in_sizes, int n_in,
                              void* d_out, int out_size, void* d_ws, size_t ws_size,
                              hipStream_t stream) {
    const float* x = (const float*)d_in[0];
    const float* W = (const float*)d_in[1];
    float* out = (float*)d_out;

    unsigned short* Bw = (unsigned short*)d_ws;                                   // 4 MB
    unsigned short* Ba = (unsigned short*)d_ws + (size_t)OUT_DIM * IN_DIM;        // +4 MB

    (void)hipFuncSetAttribute((const void*)gemm_fused,
                              hipFuncAttributeMaxDynamicSharedMemorySize, LDS_BYTES);

    prep_w<<<dim3(OUT_DIM / 32, IN_DIM / 32), dim3(32, 8), 0, stream>>>(W, Bw, Ba);
    gemm_fused<<<(B_DIM / BM) * (OUT_DIM / BN), 512, LDS_BYTES, stream>>>(x, Bw, Ba, out);
}

// Round 11
// 82.736 us; speedup vs baseline: 1.9287x; 1.9287x over previous
//
#include <hip/hip_runtime.h>
#include <hip/hip_bf16.h>

typedef __attribute__((ext_vector_type(8))) short short8;
typedef __attribute__((ext_vector_type(4))) float f32x4;
typedef __attribute__((ext_vector_type(2))) unsigned int u32x2;
typedef __attribute__((ext_vector_type(4))) unsigned int u32x4;

#define B_DIM   8192
#define IN_DIM  2048
#define OUT_DIM 1024

#define BM 256
#define BN 128
#define KS 32                      // K-step per iteration
#define NT (IN_DIM / KS)           // 64 iterations
#define A_VAR_E (BM * KS)          // 8192 elems = 16 KB per variant
#define A_BUF_E (2 * A_VAR_E)      // xm + na = 32 KB per buffer
#define B_VAR_E (BN * KS)          // 4096 elems = 8 KB (single variant: Bw)
#define LDS_BYTES ((2 * A_BUF_E + 2 * B_VAR_E) * 2)   // 81920 = 80 KiB

__device__ __forceinline__ unsigned short f2bf(float f) {
    union { float f; unsigned u; } v; v.f = f;
    unsigned u = v.u;
    unsigned r = (u + 0x7FFFu + ((u >> 16) & 1u)) >> 16;   // RNE
    return (unsigned short)r;
}

// Bw[o][i] = W[i][o]  (|W| derived in-register in the GEMM; 0.1 folded into A)
__global__ void prep_w(const float* __restrict__ W, unsigned short* __restrict__ Bw) {
    __shared__ float tile[32][33];
    int o0 = blockIdx.x * 32;
    int i0 = blockIdx.y * 32;
    int tx = threadIdx.x, ty = threadIdx.y;   // 32 x 8
    #pragma unroll
    for (int r = 0; r < 4; ++r) {
        int ii = ty + r * 8;
        tile[ii][tx] = W[(size_t)(i0 + ii) * OUT_DIM + o0 + tx];
    }
    __syncthreads();
    #pragma unroll
    for (int r = 0; r < 4; ++r) {
        int oo = ty + r * 8;
        Bw[(size_t)(o0 + oo) * IN_DIM + i0 + tx] = f2bf(tile[tx][oo]);
    }
}

// B staging (R8-proven, 0 conflicts): tile 128x32 = 8 KB = 512 threads x 16 B.
// Linear LDS dest; XOR-swizzled global SOURCE slot (rule 21).
__device__ __forceinline__ void stageB1(const unsigned short* __restrict__ g,
                                        unsigned short* lds_dst,
                                        int col0, int k0, int tid) {
    int row  = tid >> 2;                     // 0..127
    int slot = (tid & 3) ^ ((row >> 1) & 3);
    __builtin_amdgcn_global_load_lds(
        (const __attribute__((address_space(1))) void*)(g + (size_t)(col0 + row) * IN_DIM + k0 + slot * 8),
        (__attribute__((address_space(3))) void*)(lds_dst + (size_t)tid * 8),
        16, 0, 0);
}

// x -> regs, COALESCED: c = rnd*512+tid; 8 lanes cover one row's 32 f32
// (128 B contiguous per 8-lane group). 4 rounds cover 256 rows x 32 cols.
__device__ __forceinline__ void issue_x4(const float* __restrict__ x, float4* xv,
                                         int row0, int tid, int kc) {
    #pragma unroll
    for (int rnd = 0; rnd < 4; ++rnd) {
        int c    = rnd * 512 + tid;
        int row  = c >> 3;
        int col4 = c & 7;
        xv[rnd] = *reinterpret_cast<const float4*>(
            x + (size_t)(row0 + row) * IN_DIM + kc * KS + col4 * 4);
    }
}

// regs -> both bf16 A-variants in LDS (xm and -0.1|x|); 8-lane groups write
// 512 B contiguous (swizzle permutes 16 B slots within a row) -> conflict-free.
__device__ __forceinline__ void cvt_store_dual(const float4* xv,
                                               unsigned short* Abuf, int tid) {
    #pragma unroll
    for (int rnd = 0; rnd < 4; ++rnd) {
        int c    = rnd * 512 + tid;
        int row  = c >> 3;
        int col4 = c & 7;
        int eoff = row * KS + ((col4 * 4) ^ (((row >> 1) & 3) * 8));
        float4 v = xv[rnd];
        float m0 = v.x >= -1.0f ? v.x : 0.0f;
        float m1 = v.y >= -1.0f ? v.y : 0.0f;
        float m2 = v.z >= -1.0f ? v.z : 0.0f;
        float m3 = v.w >= -1.0f ? v.w : 0.0f;
        float n0 = -0.1f * fabsf(v.x), n1 = -0.1f * fabsf(v.y);
        float n2 = -0.1f * fabsf(v.z), n3 = -0.1f * fabsf(v.w);
        unsigned xm0, xm1, na0, na1;
        asm("v_cvt_pk_bf16_f32 %0, %1, %2" : "=v"(xm0) : "v"(m0), "v"(m1));
        asm("v_cvt_pk_bf16_f32 %0, %1, %2" : "=v"(xm1) : "v"(m2), "v"(m3));
        asm("v_cvt_pk_bf16_f32 %0, %1, %2" : "=v"(na0) : "v"(n0), "v"(n1));
        asm("v_cvt_pk_bf16_f32 %0, %1, %2" : "=v"(na1) : "v"(n2), "v"(n3));
        *reinterpret_cast<u32x2*>(Abuf + eoff)           = (u32x2){xm0, xm1};
        *reinterpret_cast<u32x2*>(Abuf + A_VAR_E + eoff) = (u32x2){na0, na1};
    }
}

// fragment read, inverse swizzle: slot = lq ^ ((row>>1)&3), row = KS elems
__device__ __forceinline__ short8 read_frag(const unsigned short* buf, int row,
                                            int lq) {
    int sl = lq ^ ((row >> 1) & 3);
    return *reinterpret_cast<const short8*>(buf + row * KS + sl * 8);
}

// one K=32 iteration, single barrier region (R8 cadence, R8 issue depth).
// Entry state: x(t+1) regs in flight (XCUR, 4 loads outstanding).
// Issue: B(t+1) [1 load] then x(t+2) -> XNXT [4 loads].
// cvt_store(XCUR) auto-waits x(t+1) (compiler vmcnt); manual cascade:
//   x issued   -> vmcnt(4): retires B(t+1), keeps x(t+2) in flight
//   B only     -> vmcnt(0): retires B(t+1)
//   last iter  -> no barrier (epilogue follows)
#define ITER(T_, ACUR, ANXT, BCUR, BNXT, XCUR, XNXT) do {                     \
    int t_ = (T_);                                                            \
    bool dob_ = (t_ + 1 < NT);                                                \
    bool dox_ = (t_ + 2 < NT);                                                \
    short8 fa0[4], fa1[4], fb0[4], fba[4];                                    \
    _Pragma("unroll") for (int m_ = 0; m_ < 4; ++m_) {                        \
        fa0[m_] = read_frag((ACUR),           rowA + m_ * 16, lq);            \
        fa1[m_] = read_frag((ACUR) + A_VAR_E, rowA + m_ * 16, lq);            \
    }                                                                         \
    _Pragma("unroll") for (int n_ = 0; n_ < 4; ++n_) {                        \
        fb0[n_] = read_frag((BCUR), rowB + n_ * 16, lq);                      \
        u32x4 tb_ = *reinterpret_cast<u32x4*>(&fb0[n_]);                      \
        tb_ = tb_ & 0x7FFF7FFFu;              /* |W| : clear bf16 sign bits */\
        fba[n_] = *reinterpret_cast<short8*>(&tb_);                           \
    }                                                                         \
    if (dob_) stageB1(Bw, (BNXT), col0, (t_ + 1) * KS, tid);                  \
    if (dox_) issue_x4(x, (XNXT), row0, tid, t_ + 2);                         \
    __builtin_amdgcn_s_setprio(1);                                            \
    _Pragma("unroll") for (int m_ = 0; m_ < 4; ++m_)                          \
        _Pragma("unroll") for (int n_ = 0; n_ < 4; ++n_)                      \
            acc[m_][n_] = __builtin_amdgcn_mfma_f32_16x16x32_bf16(            \
                fa0[m_], fb0[n_], acc[m_][n_], 0, 0, 0);                      \
    _Pragma("unroll") for (int m_ = 0; m_ < 4; ++m_)                          \
        _Pragma("unroll") for (int n_ = 0; n_ < 4; ++n_)                      \
            acc[m_][n_] = __builtin_amdgcn_mfma_f32_16x16x32_bf16(            \
                fa1[m_], fba[n_], acc[m_][n_], 0, 0, 0);                      \
    __builtin_amdgcn_s_setprio(0);                                            \
    if (dob_) {                                                               \
        cvt_store_dual((XCUR), (ANXT), tid);   /* x(t+1) -> A(t+1) */         \
        if (dox_) asm volatile("s_waitcnt vmcnt(4)" ::: "memory");            \
        else      asm volatile("s_waitcnt vmcnt(0)" ::: "memory");            \
        asm volatile("s_waitcnt lgkmcnt(0)" ::: "memory");                    \
        __builtin_amdgcn_s_barrier();                                         \
    }                                                                         \
} while (0)

// out[b][o] = sum_i [ mask(x)*x*W + (-0.1|x|)*|W| ] + 1e-5
__global__ __launch_bounds__(512, 2) void gemm_fused(const float* __restrict__ x,
                                                     const unsigned short* __restrict__ Bw,
                                                     float* __restrict__ C) {
    extern __shared__ __align__(16) unsigned short smem[];
    unsigned short* sA = smem;                    // [2][A_BUF_E]
    unsigned short* sB = smem + 2 * A_BUF_E;      // [2][B_VAR_E]

    // XCD colocation (R3-verified): each XCD owns 4 contiguous by-panels
    int bid = blockIdx.x;
    int xcd = bid & 7;
    int idx = bid >> 3;            // 0..31
    int by  = xcd * 4 + (idx >> 3);
    int bx  = idx & 7;
    int row0 = by * BM;
    int col0 = bx * BN;

    int tid  = threadIdx.x;
    int lane = tid & 63;
    int w    = tid >> 6;           // 0..7
    int wr   = w >> 1;             // 0..3
    int wc   = w & 1;              // 0..1
    int lr   = lane & 15;
    int lq   = lane >> 4;          // 0..3
    int rowA = wr * 64 + lr;
    int rowB = wc * 64 + lr;

    f32x4 acc[4][4];
    #pragma unroll
    for (int m = 0; m < 4; ++m)
        #pragma unroll
        for (int n = 0; n < 4; ++n)
            acc[m][n] = (f32x4){0.f, 0.f, 0.f, 0.f};

    float4 xv0[4], xv1[4];

    // prologue: B(0) staged; x(0)->xv0, x(1)->xv1 issued; A(0) <- cvt(xv0).
    // cvt forces compiler wait to x(0) (vmcnt<=4) which also retires B(0);
    // manual vmcnt(4) keeps x(1)'s 4 loads in flight.
    stageB1(Bw, sB, col0, 0, tid);
    issue_x4(x, xv0, row0, tid, 0);
    issue_x4(x, xv1, row0, tid, 1);
    cvt_store_dual(xv0, sA, tid);
    asm volatile("s_waitcnt vmcnt(4)" ::: "memory");
    asm volatile("s_waitcnt lgkmcnt(0)" ::: "memory");
    __builtin_amdgcn_s_barrier();

    // loop invariant at ITER(T): A(T) resident in ACUR; XCUR holds x(T+1);
    // XNXT is free (its previous contents consumed at iter T-1).
    #pragma unroll 1
    for (int T = 0; T < NT; T += 2) {
        ITER(T,     sA,           sA + A_BUF_E, sB,           sB + B_VAR_E, xv1, xv0);
        ITER(T + 1, sA + A_BUF_E, sA,           sB + B_VAR_E, sB,           xv0, xv1);
    }

    // epilogue: C/D layout col = lane&15, row = (lane>>4)*4 + reg
    #pragma unroll
    for (int m = 0; m < 4; ++m) {
        #pragma unroll
        for (int n = 0; n < 4; ++n) {
            int col  = col0 + wc * 64 + n * 16 + lr;
            int rowb = row0 + wr * 64 + m * 16 + lq * 4;
            #pragma unroll
            for (int j = 0; j < 4; ++j)
                C[(size_t)(rowb + j) * OUT_DIM + col] = acc[m][n][j] + 1e-5f;
        }
    }
}

extern "C" void kernel_launch(void* const* d_in, const int* in_sizes, int n_in,
                              void* d_out, int out_size, void* d_ws, size_t ws_size,
                              hipStream_t stream) {
    const float* x = (const float*)d_in[0];
    const float* W = (const float*)d_in[1];
    float* out = (float*)d_out;

    unsigned short* Bw = (unsigned short*)d_ws;    // 4 MB

    (void)hipFuncSetAttribute((const void*)gemm_fused,
                              hipFuncAttributeMaxDynamicSharedMemorySize, LDS_BYTES);

    prep_w<<<dim3(OUT_DIM / 32, IN_DIM / 32), dim3(32, 8), 0, stream>>>(W, Bw);
    gemm_fused<<<(B_DIM / BM) * (OUT_DIM / BN), 512, LDS_BYTES, stream>>>(x, Bw, out);
}

// Round 13
// 82.270 us; speedup vs baseline: 1.9396x; 1.0057x over previous
//
#include <hip/hip_runtime.h>
#include <hip/hip_bf16.h>

typedef __attribute__((ext_vector_type(8))) short short8;
typedef __attribute__((ext_vector_type(4))) float f32x4;
typedef __attribute__((ext_vector_type(2))) unsigned int u32x2;
typedef __attribute__((ext_vector_type(4))) unsigned int u32x4;

#define B_DIM   8192
#define IN_DIM  2048
#define OUT_DIM 1024

#define BM 128
#define BN 128
#define KS 32                      // K-step per iteration
#define NT (IN_DIM / KS)           // 64 iterations
#define A_VAR_E (BM * KS)          // 4096 elems = 8 KB per variant
#define A_BUF_E (2 * A_VAR_E)      // xm + na = 16 KB per buffer
#define B_VAR_E (BN * KS)          // 4096 elems = 8 KB (single variant: Bw)
#define LDS_BYTES ((2 * A_BUF_E + 2 * B_VAR_E) * 2)   // 49152 = 48 KiB -> 2+ blocks/CU

__device__ __forceinline__ unsigned short f2bf(float f) {
    union { float f; unsigned u; } v; v.f = f;
    unsigned u = v.u;
    unsigned r = (u + 0x7FFFu + ((u >> 16) & 1u)) >> 16;   // RNE
    return (unsigned short)r;
}

// Bw[o][i] = W[i][o]  (|W| derived in-register in the GEMM; 0.1 folded into A)
__global__ void prep_w(const float* __restrict__ W, unsigned short* __restrict__ Bw) {
    __shared__ float tile[32][33];
    int o0 = blockIdx.x * 32;
    int i0 = blockIdx.y * 32;
    int tx = threadIdx.x, ty = threadIdx.y;   // 32 x 8
    #pragma unroll
    for (int r = 0; r < 4; ++r) {
        int ii = ty + r * 8;
        tile[ii][tx] = W[(size_t)(i0 + ii) * OUT_DIM + o0 + tx];
    }
    __syncthreads();
    #pragma unroll
    for (int r = 0; r < 4; ++r) {
        int oo = ty + r * 8;
        Bw[(size_t)(o0 + oo) * IN_DIM + i0 + tx] = f2bf(tile[tx][oo]);
    }
}

// B staging (0 conflicts): tile 128x32 = 8 KB = 2 rounds x (256 thr x 16 B).
// Linear LDS dest; XOR-swizzled global SOURCE slot (rule 21).
__device__ __forceinline__ void stageB1(const unsigned short* __restrict__ g,
                                        unsigned short* lds_dst,
                                        int col0, int k0, int tid) {
    #pragma unroll
    for (int r = 0; r < 2; ++r) {
        int c    = r * 256 + tid;                // 0..511
        int row  = c >> 2;                       // 0..127
        int slot = (c & 3) ^ ((row >> 1) & 3);
        __builtin_amdgcn_global_load_lds(
            (const __attribute__((address_space(1))) void*)(g + (size_t)(col0 + row) * IN_DIM + k0 + slot * 8),
            (__attribute__((address_space(3))) void*)(lds_dst + (size_t)c * 8),
            16, 0, 0);
    }
}

// x -> regs, COALESCED: c = rnd*256+tid; 8 lanes cover one row's 32 f32
// (128 B contiguous per 8-lane group). 4 rounds cover 128 rows x 32 cols.
__device__ __forceinline__ void issue_x4(const float* __restrict__ x, float4* xv,
                                         int row0, int tid, int kc) {
    #pragma unroll
    for (int rnd = 0; rnd < 4; ++rnd) {
        int c    = rnd * 256 + tid;
        int row  = c >> 3;                       // 0..127
        int col4 = c & 7;
        xv[rnd] = *reinterpret_cast<const float4*>(
            x + (size_t)(row0 + row) * IN_DIM + kc * KS + col4 * 4);
    }
}

// regs -> both bf16 A-variants in LDS (xm and -0.1|x|); 8-lane groups write
// 512 B contiguous (swizzle permutes 16 B slots within a row) -> conflict-free.
__device__ __forceinline__ void cvt_store_dual(const float4* xv,
                                               unsigned short* Abuf, int tid) {
    #pragma unroll
    for (int rnd = 0; rnd < 4; ++rnd) {
        int c    = rnd * 256 + tid;
        int row  = c >> 3;
        int col4 = c & 7;
        int eoff = row * KS + ((col4 * 4) ^ (((row >> 1) & 3) * 8));
        float4 v = xv[rnd];
        float m0 = v.x >= -1.0f ? v.x : 0.0f;
        float m1 = v.y >= -1.0f ? v.y : 0.0f;
        float m2 = v.z >= -1.0f ? v.z : 0.0f;
        float m3 = v.w >= -1.0f ? v.w : 0.0f;
        float n0 = -0.1f * fabsf(v.x), n1 = -0.1f * fabsf(v.y);
        float n2 = -0.1f * fabsf(v.z), n3 = -0.1f * fabsf(v.w);
        unsigned xm0, xm1, na0, na1;
        asm("v_cvt_pk_bf16_f32 %0, %1, %2" : "=v"(xm0) : "v"(m0), "v"(m1));
        asm("v_cvt_pk_bf16_f32 %0, %1, %2" : "=v"(xm1) : "v"(m2), "v"(m3));
        asm("v_cvt_pk_bf16_f32 %0, %1, %2" : "=v"(na0) : "v"(n0), "v"(n1));
        asm("v_cvt_pk_bf16_f32 %0, %1, %2" : "=v"(na1) : "v"(n2), "v"(n3));
        *reinterpret_cast<u32x2*>(Abuf + eoff)           = (u32x2){xm0, xm1};
        *reinterpret_cast<u32x2*>(Abuf + A_VAR_E + eoff) = (u32x2){na0, na1};
    }
}

// fragment read, inverse swizzle: slot = lq ^ ((row>>1)&3), row = KS elems
__device__ __forceinline__ short8 read_frag(const unsigned short* buf, int row,
                                            int lq) {
    int sl = lq ^ ((row >> 1) & 3);
    return *reinterpret_cast<const short8*>(buf + row * KS + sl * 8);
}

// one K=32 iteration. RACE FIX (R13): B's global_load_lds are issued FIRST
// and pinned oldest in the VM queue via sched_barrier(0) so the manual
// vmcnt(4) deterministically retires the B DMA (not the x prefetch),
// regardless of compiler scheduling. Entry: x(t+1) in XCUR (4 loads, may be
// outstanding). Issue: B(t+1) [2 loads, pinned first], x(t+2)->XNXT [4].
// cvt_store(XCUR) compiler-waits x(t+1); manual cascade:
//   dox -> vmcnt(4): retires B(t+1), keeps x(t+2) in flight
//   else dob -> vmcnt(0); last iter -> fall through to epilogue.
#define ITER(T_, ACUR, ANXT, BCUR, BNXT, XCUR, XNXT) do {                     \
    int t_ = (T_);                                                            \
    bool dob_ = (t_ + 1 < NT);                                                \
    bool dox_ = (t_ + 2 < NT);                                                \
    if (dob_) stageB1(Bw, (BNXT), col0, (t_ + 1) * KS, tid);                  \
    __builtin_amdgcn_sched_barrier(0);   /* pin: B DMA oldest in VM queue */  \
    short8 fa0[4], fa1[4], fb0[4], fba[4];                                    \
    _Pragma("unroll") for (int m_ = 0; m_ < 4; ++m_) {                        \
        fa0[m_] = read_frag((ACUR),           rowA + m_ * 16, lq);            \
        fa1[m_] = read_frag((ACUR) + A_VAR_E, rowA + m_ * 16, lq);            \
    }                                                                         \
    _Pragma("unroll") for (int n_ = 0; n_ < 4; ++n_) {                        \
        fb0[n_] = read_frag((BCUR), rowB + n_ * 16, lq);                      \
        u32x4 tb_ = *reinterpret_cast<u32x4*>(&fb0[n_]);                      \
        tb_ = tb_ & 0x7FFF7FFFu;              /* |W| : clear bf16 sign bits */\
        fba[n_] = *reinterpret_cast<short8*>(&tb_);                           \
    }                                                                         \
    if (dox_) issue_x4(x, (XNXT), row0, tid, t_ + 2);                         \
    __builtin_amdgcn_s_setprio(1);                                            \
    _Pragma("unroll") for (int m_ = 0; m_ < 4; ++m_)                          \
        _Pragma("unroll") for (int n_ = 0; n_ < 4; ++n_)                      \
            acc[m_][n_] = __builtin_amdgcn_mfma_f32_16x16x32_bf16(            \
                fa0[m_], fb0[n_], acc[m_][n_], 0, 0, 0);                      \
    _Pragma("unroll") for (int m_ = 0; m_ < 4; ++m_)                          \
        _Pragma("unroll") for (int n_ = 0; n_ < 4; ++n_)                      \
            acc[m_][n_] = __builtin_amdgcn_mfma_f32_16x16x32_bf16(            \
                fa1[m_], fba[n_], acc[m_][n_], 0, 0, 0);                      \
    __builtin_amdgcn_s_setprio(0);                                            \
    if (dob_) {                                                               \
        cvt_store_dual((XCUR), (ANXT), tid);   /* x(t+1) -> A(t+1) */         \
        if (dox_) asm volatile("s_waitcnt vmcnt(4)" ::: "memory");            \
        else      asm volatile("s_waitcnt vmcnt(0)" ::: "memory");            \
        asm volatile("s_waitcnt lgkmcnt(0)" ::: "memory");                    \
        __builtin_amdgcn_s_barrier();                                         \
    }                                                                         \
} while (0)

// out[b][o] = sum_i [ mask(x)*x*W + (-0.1|x|)*|W| ] + 1e-5
__global__ __launch_bounds__(256, 2) void gemm_fused(const float* __restrict__ x,
                                                     const unsigned short* __restrict__ Bw,
                                                     float* __restrict__ C) {
    extern __shared__ __align__(16) unsigned short smem[];
    unsigned short* sA = smem;                    // [2][A_BUF_E]
    unsigned short* sB = smem + 2 * A_BUF_E;      // [2][B_VAR_E]

    // XCD colocation: nwg=512, each XCD owns 8 contiguous by-panels x 8 bx
    int bid = blockIdx.x;
    int xcd = bid & 7;
    int idx = bid >> 3;            // 0..63
    int by  = xcd * 8 + (idx >> 3);
    int bx  = idx & 7;
    int row0 = by * BM;
    int col0 = bx * BN;

    int tid  = threadIdx.x;
    int lane = tid & 63;
    int w    = tid >> 6;           // 0..3
    int wr   = w >> 1;             // 0..1
    int wc   = w & 1;              // 0..1
    int lr   = lane & 15;
    int lq   = lane >> 4;          // 0..3
    int rowA = wr * 64 + lr;
    int rowB = wc * 64 + lr;

    f32x4 acc[4][4];
    #pragma unroll
    for (int m = 0; m < 4; ++m)
        #pragma unroll
        for (int n = 0; n < 4; ++n)
            acc[m][n] = (f32x4){0.f, 0.f, 0.f, 0.f};

    float4 xv0[4], xv1[4];

    // prologue: B(0) staged (pinned oldest); x(0)->xv0, x(1)->xv1 issued;
    // A(0) <- cvt(xv0). cvt's compiler wait (retire x(0)) also retires B(0)
    // because B(0) is pinned older; manual vmcnt(4) keeps x(1) in flight.
    stageB1(Bw, sB, col0, 0, tid);
    __builtin_amdgcn_sched_barrier(0);   // pin: B(0) DMA oldest
    issue_x4(x, xv0, row0, tid, 0);
    issue_x4(x, xv1, row0, tid, 1);
    cvt_store_dual(xv0, sA, tid);
    asm volatile("s_waitcnt vmcnt(4)" ::: "memory");
    asm volatile("s_waitcnt lgkmcnt(0)" ::: "memory");
    __builtin_amdgcn_s_barrier();

    // loop invariant at ITER(T): A(T) resident in ACUR; XCUR holds x(T+1)
    #pragma unroll 1
    for (int T = 0; T < NT; T += 2) {
        ITER(T,     sA,           sA + A_BUF_E, sB,           sB + B_VAR_E, xv1, xv0);
        ITER(T + 1, sA + A_BUF_E, sA,           sB + B_VAR_E, sB,           xv0, xv1);
    }

    // epilogue: C/D layout col = lane&15, row = (lane>>4)*4 + reg
    #pragma unroll
    for (int m = 0; m < 4; ++m) {
        #pragma unroll
        for (int n = 0; n < 4; ++n) {
            int col  = col0 + wc * 64 + n * 16 + lr;
            int rowb = row0 + wr * 64 + m * 16 + lq * 4;
            #pragma unroll
            for (int j = 0; j < 4; ++j)
                C[(size_t)(rowb + j) * OUT_DIM + col] = acc[m][n][j] + 1e-5f;
        }
    }
}

extern "C" void kernel_launch(void* const* d_in, const int* in_sizes, int n_in,
                              void* d_out, int out_size, void* d_ws, size_t ws_size,
                              hipStream_t stream) {
    const float* x = (const float*)d_in[0];
    const float* W = (const float*)d_in[1];
    float* out = (float*)d_out;

    unsigned short* Bw = (unsigned short*)d_ws;    // 4 MB

    (void)hipFuncSetAttribute((const void*)gemm_fused,
                              hipFuncAttributeMaxDynamicSharedMemorySize, LDS_BYTES);

    prep_w<<<dim3(OUT_DIM / 32, IN_DIM / 32), dim3(32, 8), 0, stream>>>(W, Bw);
    gemm_fused<<<(B_DIM / BM) * (OUT_DIM / BN), 256, LDS_BYTES, stream>>>(x, Bw, out);
}